// Round 5
// 36636.899 us; speedup vs baseline: 1.8246x; 1.8246x over previous
//
#include <hip/hip_runtime.h>
#include <math.h>

#define WORDN 1024
#define HIDN  2048
#define ENCN  512
#define NODEN 8192
#define NSTEP (NODEN - 1)

#define CHAIN_WGS 32
#define SENTU 0x7F7F7F7Fu   // memset byte 0x7F -> float 3.39e38; tanh outputs / N(0,1) seeds can never hit this

// ---------------------------------------------------------------------------
// Persistent sequential-chain kernel: P[t+1] = tanh(W @ P[t] + addv_t)
// 32 WGs x 256 threads. Each WG owns 32 output rows; weights held in VGPRs
// (128 floats per thread).
//
// Synchronization: SENTINEL DATAFLOW (no barrier, no fences). Each slot of
// the P history buffer is written exactly once. The buffer is pre-poisoned
// with 0x7F7F7F7F. Producers write results with relaxed agent-scope stores
// (bypass per-XCD L2, land at the LLC); each consumer polls its own 4
// elements of P[t] with relaxed agent-scope loads until none is the
// sentinel. The value IS the ready flag, so per-step cost is one LLC
// store->load round trip instead of 32 serialized atomics + L2 wb/inv.
// ---------------------------------------------------------------------------
__global__ __launch_bounds__(256, 1) void chain_kernel(
    const float* __restrict__ W, int ldw, int row_off,
    const float* __restrict__ addv, long addv_stride,
    float* __restrict__ P)
{
  const int g    = blockIdx.x;      // 0..31
  const int tid  = threadIdx.x;     // 0..255
  const int lane = tid & 63;
  const int wave = tid >> 6;
  const int rloc = (wave << 3) | (lane >> 3);  // 0..31 row within WG
  const int row  = (g << 5) | rloc;            // 0..1023
  const int seg  = lane & 7;                   // 128-col segment

  // Load this lane's 128 weights into registers (one-time).
  float4 w[32];
  {
    const float* wr = W + (long)(row_off + row) * ldw + (seg << 7);
    #pragma unroll
    for (int i = 0; i < 32; ++i) w[i] = ((const float4*)wr)[i];
  }

  __shared__ float lds[8 * 132];  // 8 segments x (128 + 4 pad) -> conflict-free

  const unsigned int* __restrict__ Pu = (const unsigned int*)P;

  for (int t = 0; t < NSTEP; ++t) {
    // Additive term: plain cached load (read-only input, visible since
    // it was produced by an earlier dispatch). Issue before the poll.
    float av = addv[(long)t * addv_stride + row];

    // Poll this thread's 4 parent elements at agent scope (LLC dataflow).
    const unsigned int* ps = Pu + ((long)t << 10) + (tid << 2);
    unsigned int a, b, c, d;
    for (;;) {
      a = __hip_atomic_load(ps + 0, __ATOMIC_RELAXED, __HIP_MEMORY_SCOPE_AGENT);
      b = __hip_atomic_load(ps + 1, __ATOMIC_RELAXED, __HIP_MEMORY_SCOPE_AGENT);
      c = __hip_atomic_load(ps + 2, __ATOMIC_RELAXED, __HIP_MEMORY_SCOPE_AGENT);
      d = __hip_atomic_load(ps + 3, __ATOMIC_RELAXED, __HIP_MEMORY_SCOPE_AGENT);
      if ((a != SENTU) & (b != SENTU) & (c != SENTU) & (d != SENTU)) break;
    }

    // Stage into LDS (same conflict-free layout as before).
    {
      int j = tid << 2;
      float4 pv = make_float4(__uint_as_float(a), __uint_as_float(b),
                              __uint_as_float(c), __uint_as_float(d));
      *(float4*)&lds[((j >> 7) * 132) + (j & 127)] = pv;
    }
    __syncthreads();

    float acc = 0.f;
    const float* lb = &lds[seg * 132];
    #pragma unroll
    for (int i = 0; i < 32; ++i) {
      float4 p4 = *(const float4*)(lb + (i << 2));
      acc = fmaf(w[i].x, p4.x, acc);
      acc = fmaf(w[i].y, p4.y, acc);
      acc = fmaf(w[i].z, p4.z, acc);
      acc = fmaf(w[i].w, p4.w, acc);
    }
    // Reduce across the 8 lanes sharing a row (seg bits = lane bits 0..2).
    acc += __shfl_xor(acc, 1);
    acc += __shfl_xor(acc, 2);
    acc += __shfl_xor(acc, 4);
    if (seg == 0) {
      float v = tanhf(acc + av);
      // Agent-scope store: bypasses this XCD's L2, visible at the LLC.
      __hip_atomic_store(&P[((long)(t + 1) << 10) + row], v,
                         __ATOMIC_RELAXED, __HIP_MEMORY_SCOPE_AGENT);
    }
    __syncthreads();  // protect LDS before next iteration's staging
  }
}

// ---------------------------------------------------------------------------
// Wave-per-row matvec: y[r] = tanh(W[row_off+r,:] . x + b[b_off+r])
// ---------------------------------------------------------------------------
__global__ void matvec_tanh(const float* __restrict__ W, int ldw, int row_off,
                            const float* __restrict__ x, int K,
                            const float* __restrict__ b, int b_off,
                            float* __restrict__ y, int M)
{
  int gw   = (int)((blockIdx.x * blockDim.x + threadIdx.x) >> 6);
  int lane = threadIdx.x & 63;
  if (gw >= M) return;
  const float* wr = W + (long)(row_off + gw) * ldw;
  float acc = 0.f;
  for (int k = lane << 2; k < K; k += 256) {
    float4 wv = *(const float4*)(wr + k);
    float4 xv = *(const float4*)(x + k);
    acc = fmaf(wv.x, xv.x, acc);
    acc = fmaf(wv.y, xv.y, acc);
    acc = fmaf(wv.z, xv.z, acc);
    acc = fmaf(wv.w, xv.w, acc);
  }
  #pragma unroll
  for (int off = 1; off < 64; off <<= 1) acc += __shfl_xor(acc, off);
  if (lane == 0) y[gw] = tanhf(acc + b[b_off + gw]);
}

// z = eps * exp(0.5*va) + mu   (512 elements)
__global__ void z_kernel(const float* __restrict__ eps, const float* __restrict__ mu,
                         const float* __restrict__ va, float* __restrict__ z)
{
  int i = blockIdx.x * blockDim.x + threadIdx.x;
  z[i] = eps[i] * expf(0.5f * va[i]) + mu[i];
}

// ---------------------------------------------------------------------------
// fp32 tiled GEMM: C[crow(m), n] = (tanh?)( sum_k A[a_row0+m, k]*B[b_row0+n, k] + bias[n] )
// crow(m) = rev ? (M - m) : m.   BM=BN=128, BK=8, 256 threads, 8x8 microtile.
// ---------------------------------------------------------------------------
#define GBM 128
#define GBN 128
#define GBK 8

__global__ __launch_bounds__(256, 2) void gemm_bt(
    const float* __restrict__ A, long lda, long a_row0,
    const float* __restrict__ B, long ldb, long b_row0,
    const float* __restrict__ bias, long bias_off,
    float* __restrict__ C, long ldc,
    int M, int N, int K, int rev, int do_tanh)
{
  __shared__ float As[GBK][GBM + 4];
  __shared__ float Bs[GBK][GBN + 4];

  const int tid = threadIdx.x;
  const int bm = blockIdx.x, bn = blockIdx.y;
  const int tx = tid & 15;    // n dir
  const int ty = tid >> 4;    // m dir
  const int lr = tid >> 1;          // 0..127 staging row
  const int lc = (tid & 1) << 2;    // 0 or 4 staging col

  float acc[8][8];
  #pragma unroll
  for (int i = 0; i < 8; ++i)
    #pragma unroll
    for (int j = 0; j < 8; ++j) acc[i][j] = 0.f;

  for (int k0 = 0; k0 < K; k0 += GBK) {
    int am = bm * GBM + lr;
    float4 avv = make_float4(0.f, 0.f, 0.f, 0.f);
    if (am < M) avv = *(const float4*)(A + (a_row0 + am) * lda + k0 + lc);
    int bnr = bn * GBN + lr;
    float4 bvv = *(const float4*)(B + (b_row0 + bnr) * ldb + k0 + lc);

    As[lc + 0][lr] = avv.x; As[lc + 1][lr] = avv.y;
    As[lc + 2][lr] = avv.z; As[lc + 3][lr] = avv.w;
    Bs[lc + 0][lr] = bvv.x; Bs[lc + 1][lr] = bvv.y;
    Bs[lc + 2][lr] = bvv.z; Bs[lc + 3][lr] = bvv.w;
    __syncthreads();

    #pragma unroll
    for (int k = 0; k < GBK; ++k) {
      float4 a0 = *(const float4*)&As[k][ty << 2];
      float4 a1 = *(const float4*)&As[k][64 + (ty << 2)];
      float4 b0 = *(const float4*)&Bs[k][tx << 2];
      float4 b1 = *(const float4*)&Bs[k][64 + (tx << 2)];
      float aa[8] = {a0.x, a0.y, a0.z, a0.w, a1.x, a1.y, a1.z, a1.w};
      float bb[8] = {b0.x, b0.y, b0.z, b0.w, b1.x, b1.y, b1.z, b1.w};
      #pragma unroll
      for (int i = 0; i < 8; ++i)
        #pragma unroll
        for (int j = 0; j < 8; ++j)
          acc[i][j] = fmaf(aa[i], bb[j], acc[i][j]);
    }
    __syncthreads();
  }

  // Epilogue
  #pragma unroll
  for (int hm = 0; hm < 2; ++hm) {
    #pragma unroll
    for (int i = 0; i < 4; ++i) {
      int m = bm * GBM + hm * 64 + (ty << 2) + i;
      if (m >= M) continue;
      long crow = rev ? (long)(M - m) : (long)m;
      #pragma unroll
      for (int hn = 0; hn < 2; ++hn) {
        int n0 = bn * GBN + hn * 64 + (tx << 2);
        float4 v;
        v.x = acc[hm * 4 + i][hn * 4 + 0] + bias[bias_off + n0 + 0];
        v.y = acc[hm * 4 + i][hn * 4 + 1] + bias[bias_off + n0 + 1];
        v.z = acc[hm * 4 + i][hn * 4 + 2] + bias[bias_off + n0 + 2];
        v.w = acc[hm * 4 + i][hn * 4 + 3] + bias[bias_off + n0 + 3];
        if (do_tanh) {
          v.x = tanhf(v.x); v.y = tanhf(v.y); v.z = tanhf(v.z); v.w = tanhf(v.w);
        }
        *(float4*)(C + crow * ldc + n0) = v;
      }
    }
  }
}

// ---------------------------------------------------------------------------
extern "C" void kernel_launch(void* const* d_in, const int* in_sizes, int n_in,
                              void* d_out, int out_size, void* d_ws, size_t ws_size,
                              hipStream_t stream)
{
  const float* sent    = (const float*)d_in[0];
  const float* eps     = (const float*)d_in[1];
  const float* WeC2P_w = (const float*)d_in[2];
  const float* WeC2P_b = (const float*)d_in[3];
  const float* WeP2H_w = (const float*)d_in[4];
  const float* WeP2H_b = (const float*)d_in[5];
  const float* WeH2M_w = (const float*)d_in[6];
  const float* WeH2M_b = (const float*)d_in[7];
  const float* WeH2D_w = (const float*)d_in[8];
  const float* WeH2D_b = (const float*)d_in[9];
  const float* WdE2H_w = (const float*)d_in[10];
  const float* WdE2H_b = (const float*)d_in[11];
  const float* WdH2P_w = (const float*)d_in[12];
  const float* WdH2P_b = (const float*)d_in[13];
  const float* WdP2C_w = (const float*)d_in[14];
  const float* WdP2C_b = (const float*)d_in[15];
  float* out = (float*)d_out;

  char* ws = (char*)d_ws;
  float* hid  = (float*)(ws + 256);                  // 2048
  float* mu   = hid + HIDN;                          // 512
  float* va   = mu + ENCN;                           // 512
  float* z    = va + ENCN;                           // 512
  float* hdec = z + ENCN;                            // 2048
  float* P    = (float*)(ws + 65536);                // 8192 x 1024 fp32 (32 MB)

  // Poison the full P history with the sentinel byte pattern, then seed
  // P[0] = sent[0] (encode seed). Every P slot is written exactly once.
  hipMemsetAsync(P, 0x7F, (size_t)NODEN * WORDN * sizeof(float), stream);
  hipMemcpyAsync(P, sent, WORDN * sizeof(float), hipMemcpyDeviceToDevice, stream);

  dim3 gg((NSTEP + GBM - 1) / GBM, WORDN / GBN);  // (64, 8)

  // U[t] = Wx @ sent[t+1] + b_enc   -> stored in d_out (scratch; overwritten later)
  gemm_bt<<<gg, 256, 0, stream>>>(sent, WORDN, 1,
                                  WeC2P_w + WORDN, 2 * WORDN, 0,
                                  WeC2P_b, 0,
                                  out, WORDN,
                                  NSTEP, WORDN, WORDN, 0, 0);

  // Encode chain: P[t+1] = tanh(Wp @ P[t] + U[t]),  t = 0..8190
  chain_kernel<<<CHAIN_WGS, 256, 0, stream>>>(WeC2P_w, 2 * WORDN, 0,
                                              out, WORDN, P);

  // hid = tanh(WeP2H @ P[8191] + b)
  matvec_tanh<<<(HIDN * 64) / 256, 256, 0, stream>>>(WeP2H_w, WORDN, 0,
                                                     P + (long)NSTEP * WORDN, WORDN,
                                                     WeP2H_b, 0, hid, HIDN);

  // Re-poison rows 1..NSTEP for the decode chain (row 0 is rewritten below).
  hipMemsetAsync(P + WORDN, 0x7F, (size_t)NSTEP * WORDN * sizeof(float), stream);

  // mu, va
  matvec_tanh<<<(ENCN * 64) / 256, 256, 0, stream>>>(WeH2M_w, HIDN, 0, hid, HIDN,
                                                     WeH2M_b, 0, mu, ENCN);
  matvec_tanh<<<(ENCN * 64) / 256, 256, 0, stream>>>(WeH2D_w, HIDN, 0, hid, HIDN,
                                                     WeH2D_b, 0, va, ENCN);
  // z = eps * exp(0.5 va) + mu
  z_kernel<<<ENCN / 256, 256, 0, stream>>>(eps, mu, va, z);
  // hdec = tanh(WdE2H @ z + b)
  matvec_tanh<<<(HIDN * 64) / 256, 256, 0, stream>>>(WdE2H_w, ENCN, 0, z, ENCN,
                                                     WdE2H_b, 0, hdec, HIDN);
  // parent_d = tanh(WdH2P @ hdec + b)  -> P[0]  (decode seed)
  matvec_tanh<<<(WORDN * 64) / 256, 256, 0, stream>>>(WdH2P_w, HIDN, 0, hdec, HIDN,
                                                      WdH2P_b, 0, P, WORDN);

  // Decode chain: P[t+1] = tanh(Wbot @ P[t] + b_bot), t = 0..8190
  chain_kernel<<<CHAIN_WGS, 256, 0, stream>>>(WdP2C_w, WORDN, WORDN,
                                              WdP2C_b + WORDN, 0, P);

  // out[8191 - i] = tanh(Wtop @ P[i] + b_top), i = 0..8190
  gemm_bt<<<gg, 256, 0, stream>>>(P, WORDN, 0,
                                  WdP2C_w, WORDN, 0,
                                  WdP2C_b, 0,
                                  out, WORDN,
                                  NSTEP, WORDN, WORDN, 1, 1);

  // out[0] = p_8191
  hipMemcpyAsync(out, P + (long)NSTEP * WORDN, WORDN * sizeof(float),
                 hipMemcpyDeviceToDevice, stream);
}